// Round 8
// baseline (774.034 us; speedup 1.0000x reference)
//
#include <hip/hip_runtime.h>

#define S_LEN  2048
#define BATCH  1024
#define NL     6
#define NS     2       // software-interleaved streams per wave
#define CH     8       // timesteps per chunk
#define NCHUNK 257     // 257*8 = 2056 >= 2048 + NL - 1 = 2053 steps

__device__ __forceinline__ float fexp2(float x) { return __builtin_amdgcn_exp2f(x); }
__device__ __forceinline__ float frcp(float x)  { return __builtin_amdgcn_rcpf(x); }

// quad_perm DPP: xor1=[1,0,3,2]=0xB1, xor2=[2,3,0,1]=0x4E, xor3=[3,2,1,0]=0x1B
template <int CTRL>
__device__ __forceinline__ float dppf(float v) {
    return __int_as_float(__builtin_amdgcn_update_dpp(
        0, __float_as_int(v), CTRL, 0xF, 0xF, true));
}
__device__ __forceinline__ float bpermf(int addr, float v) {
    return __int_as_float(__builtin_amdgcn_ds_bpermute(addr, __float_as_int(v)));
}

// ONE wave carries the whole 6-layer pipeline for 2 independent STREAMS of 2
// batch elements each (weights shared in registers). The two streams' serial
// chains are independent -> the scheduler fills one stream's latency stalls
// (8-deep FMA chain, exp/rcp chains, bpermute) with the other's issue.
// lane = L*8 + e*4 + j; lanes 56-63 feeders (publish x[t]); skew-1 pipeline:
// at step n, layer L computes t=n-L; handoff via end-of-step ds_bpermute.
// Cell update folded to 3 exp + 1 rcp (exact algebra, operands >= 1):
//   c' = [c*B*D + A*(E-1)] / (A*B*D),  A=1+e^-f, B=1+e^-i, E=e^{2g}, D=E+1
// h kept in the +/-inf-robust form: h = sig(o) * (2*rcp(1+e^{-2c'}) - 1).
template <bool GUARD>
__device__ __forceinline__ void run_chunk(
    int cc, int& tc, float (&h)[NS], float (&c)[NS], float (&hupn)[NS],
    const float (&Wx)[4][4], const float (&Wh)[4][4], const float (&Gb)[4],
    float (&xu)[NS][CH], float regw, float regb, int bpaddr, bool isFeeder,
    bool isOut, const int (&bb)[NS], const size_t (&xoff)[NS],
    const float* __restrict__ x, float* __restrict__ out) {
    float xp[NS][CH];
#pragma unroll
    for (int s = 0; s < NS; ++s)
#pragma unroll
        for (int u = 0; u < CH; ++u) {   // prefetch next chunk (feeder = x[n+1])
            int t2 = (cc + 1) * CH + u + 1;
            if (t2 > S_LEN - 1) t2 = S_LEN - 1;
            xp[s][u] = x[(size_t)t2 * 4096 + xoff[s]];
        }
    float su[NS][CH];
#pragma unroll
    for (int u = 0; u < CH; ++u) {
        // ---- own-h section, both streams (independent of in-flight bperms) --
        float hv1[NS], hv2[NS], hv3[NS], Hi[NS], Hf[NS], Hg[NS], Ho[NS];
#pragma unroll
        for (int s = 0; s < NS; ++s) {
            hv1[s] = dppf<0xB1>(h[s]);
            hv2[s] = dppf<0x4E>(h[s]);
            hv3[s] = dppf<0x1B>(h[s]);
        }
#pragma unroll
        for (int s = 0; s < NS; ++s) {
            Hi[s] = fmaf(Wh[0][0], h[s], Gb[0]);
            Hf[s] = fmaf(Wh[1][0], h[s], Gb[1]);
            Hg[s] = fmaf(Wh[2][0], h[s], Gb[2]);
            Ho[s] = fmaf(Wh[3][0], h[s], Gb[3]);
            Hi[s] = fmaf(Wh[0][1], hv1[s], Hi[s]); Hf[s] = fmaf(Wh[1][1], hv1[s], Hf[s]);
            Hg[s] = fmaf(Wh[2][1], hv1[s], Hg[s]); Ho[s] = fmaf(Wh[3][1], hv1[s], Ho[s]);
            Hi[s] = fmaf(Wh[0][2], hv2[s], Hi[s]); Hf[s] = fmaf(Wh[1][2], hv2[s], Hf[s]);
            Hg[s] = fmaf(Wh[2][2], hv2[s], Hg[s]); Ho[s] = fmaf(Wh[3][2], hv2[s], Ho[s]);
            Hi[s] = fmaf(Wh[0][3], hv3[s], Hi[s]); Hf[s] = fmaf(Wh[1][3], hv3[s], Hf[s]);
            Hg[s] = fmaf(Wh[2][3], hv3[s], Hg[s]); Ho[s] = fmaf(Wh[3][3], hv3[s], Ho[s]);
        }
        // ---- consume the bpermutes issued at the end of the previous step ---
        float hn[NS], cn[NS];
#pragma unroll
        for (int s = 0; s < NS; ++s) {
            const float hup = hupn[s];
            const float xv1 = dppf<0xB1>(hup), xv2 = dppf<0x4E>(hup), xv3 = dppf<0x1B>(hup);
            float Xi = Wx[0][0] * hup, Xf = Wx[1][0] * hup;
            float Xg = Wx[2][0] * hup, Xo = Wx[3][0] * hup;
            Xi = fmaf(Wx[0][1], xv1, Xi); Xf = fmaf(Wx[1][1], xv1, Xf);
            Xg = fmaf(Wx[2][1], xv1, Xg); Xo = fmaf(Wx[3][1], xv1, Xo);
            Xi = fmaf(Wx[0][2], xv2, Xi); Xf = fmaf(Wx[1][2], xv2, Xf);
            Xg = fmaf(Wx[2][2], xv2, Xg); Xo = fmaf(Wx[3][2], xv2, Xo);
            Xi = fmaf(Wx[0][3], xv3, Xi); Xf = fmaf(Wx[1][3], xv3, Xf);
            Xg = fmaf(Wx[2][3], xv3, Xg); Xo = fmaf(Wx[3][3], xv3, Xo);
            const float Gi = Hi[s] + Xi, Gf = Hf[s] + Xf;
            const float Gg = Hg[s] + Xg, Go = Ho[s] + Xo;
            // folded cell: 3 exp + 1 rcp
            const float emi = fexp2(Gi * -1.442695041f);
            const float emf = fexp2(Gf * -1.442695041f);
            const float e2g = fexp2(Gg *  2.885390082f);
            const float A = 1.0f + emf, B = 1.0f + emi, D = e2g + 1.0f;
            const float BD = B * D;
            const float rc = frcp(A * BD);
            const float num = fmaf(c[s], BD, A * (e2g - 1.0f));
            cn[s] = num * rc;
            // robust h: 2 exp + 2 rcp
            const float em2c = fexp2(cn[s] * -2.885390082f);
            const float tanc = fmaf(2.0f, frcp(1.0f + em2c), -1.0f);
            const float emo  = fexp2(Go * -1.442695041f);
            hn[s] = frcp(1.0f + emo) * tanc;
        }
        // ---- update, publish, issue next bpermutes ----
        if (GUARD) ++tc;
        const bool act = !GUARD || ((unsigned)tc < (unsigned)S_LEN);
#pragma unroll
        for (int s = 0; s < NS; ++s) {
            c[s] = act ? cn[s] : c[s];
            h[s] = act ? hn[s] : h[s];
            h[s] = isFeeder ? xu[s][u] : h[s];   // feeders publish x[n+1]
            hupn[s] = bpermf(bpaddr, h[s]);      // consumed next step
            su[s][u] = h[s];                     // L5 lanes: == hn
        }
    }
    // ---- chunk drain: head reduce + store (independent chains) ----
    const int base = cc * CH - (NL - 1);
#pragma unroll
    for (int s = 0; s < NS; ++s)
#pragma unroll
        for (int u = 0; u < CH; ++u) {
            float v = su[s][u] * regw;
            v += dppf<0xB1>(v);
            v += dppf<0x4E>(v);
            v += regb;
            const int t = base + u;
            if (isOut && t >= 0 && t < S_LEN) out[(size_t)t * BATCH + bb[s]] = v;
        }
#pragma unroll
    for (int s = 0; s < NS; ++s)
#pragma unroll
        for (int u = 0; u < CH; ++u) xu[s][u] = xp[s][u];
}

__global__ __launch_bounds__(64, 1) void lstm_wavepipe6(
    const float* __restrict__ x, const float* __restrict__ w_ih,
    const float* __restrict__ w_hh, const float* __restrict__ b_ih,
    const float* __restrict__ b_hh, const float* __restrict__ reg_w,
    const float* __restrict__ reg_b, float* __restrict__ out) {
    const int lane = threadIdx.x;
    const int L    = lane >> 3;
    const int e    = (lane >> 2) & 1;
    const int j    = lane & 3;
    const int Lc   = (L < NL) ? L : NL - 1;      // clamp for safe weight loads
    const bool isFeeder = (lane >= 56);
    const bool isOut    = (L == 5) && (j == 0);

    // ---- shared weight preload (term m multiplies value of unit j^m) ----
    float Wx[4][4], Wh[4][4], Gb[4];
#pragma unroll
    for (int g = 0; g < 4; ++g) {
        const int row = Lc * 16 + g * 4 + j;     // PyTorch gate order i,f,g,o
#pragma unroll
        for (int m = 0; m < 4; ++m) {
            Wx[g][m] = w_ih[row * 4 + (j ^ m)];
            Wh[g][m] = w_hh[row * 4 + (j ^ m)];
        }
        Gb[g] = b_ih[row] + b_hh[row];
    }
    const float regw = reg_w[j];
    const float regb = reg_b[0];
    const int bpaddr = ((lane >= 8) ? (lane - 8) : (lane + 56)) << 2;
    int tc = (L < NL) ? (-L - 1) : -2100000000;

    int bb[NS];
    size_t xoff[NS];
    float h[NS] = {0.0f, 0.0f}, c[NS] = {0.0f, 0.0f}, hupn[NS];
    float xu[NS][CH];
#pragma unroll
    for (int s = 0; s < NS; ++s) {
        bb[s]   = blockIdx.x * (2 * NS) + s * 2 + e;
        xoff[s] = (size_t)(bb[s] * 4 + j);       // x[t*4096 + 4b + j]
#pragma unroll
        for (int u = 0; u < CH; ++u) {           // xu[u] = x[u+1]
            int t2 = u + 1; if (t2 > S_LEN - 1) t2 = S_LEN - 1;
            xu[s][u] = x[(size_t)t2 * 4096 + xoff[s]];
        }
    }
    // prime the handoff: step-0 inputs (L0 <- x[0]; L>0 <- h=0)
#pragma unroll
    for (int s = 0; s < NS; ++s) {
        const float fh = isFeeder ? x[xoff[s]] : 0.0f;
        hupn[s] = bpermf(bpaddr, fh);
    }

    run_chunk<true>(0, tc, h, c, hupn, Wx, Wh, Gb, xu, regw, regb, bpaddr,
                    isFeeder, isOut, bb, xoff, x, out);
    for (int cc = 1; cc < NCHUNK; ++cc)
        run_chunk<false>(cc, tc, h, c, hupn, Wx, Wh, Gb, xu, regw, regb,
                         bpaddr, isFeeder, isOut, bb, xoff, x, out);
}

extern "C" void kernel_launch(void* const* d_in, const int* in_sizes, int n_in,
                              void* d_out, int out_size, void* d_ws, size_t ws_size,
                              hipStream_t stream) {
    const float* x     = (const float*)d_in[0];
    const float* w_ih  = (const float*)d_in[1];
    const float* w_hh  = (const float*)d_in[2];
    const float* b_ih  = (const float*)d_in[3];
    const float* b_hh  = (const float*)d_in[4];
    const float* reg_w = (const float*)d_in[5];
    const float* reg_b = (const float*)d_in[6];
    float* out = (float*)d_out;

    // 256 single-wave blocks, 4 batch elements (2 streams x 2) per wave.
    dim3 grid(BATCH / (2 * NS));
    dim3 block(64);
    hipLaunchKernelGGL(lstm_wavepipe6, grid, block, 0, stream, x, w_ih, w_hh,
                       b_ih, b_hh, reg_w, reg_b, out);
}